// Round 1
// baseline (25685.703 us; speedup 1.0000x reference)
//
#include <hip/hip_runtime.h>
#include <hip/hip_fp16.h>
#include <cstddef>

#define BB 64
#define LL 512
#define II 256
#define HH 512

typedef _Float16 half_t;
typedef _Float16 h2 __attribute__((ext_vector_type(2)));
typedef float f4 __attribute__((ext_vector_type(4)));

// d_ws layout, in h2 (4-byte) units:
//   W0T2 : [256][512]   k-pair-major, dw0 transposed   @ 0
//   W1T2 : [256][512]                                   @ 131072
//   WhhT2: [256][1536]                                  @ 262144
//   WihT2: [128][1536]                                  @ 655360
#define W0_OFF   0
#define W1_OFF   131072
#define WHH_OFF  262144
#define WIH_OFF  655360
#define WS_H2_TOTAL 851968

__device__ __forceinline__ float dot2f(h2 a, h2 b, float c) {
#if defined(__has_builtin)
#if __has_builtin(__builtin_amdgcn_fdot2)
    return __builtin_amdgcn_fdot2(a, b, c, false);
#else
    return c + (float)a.x * (float)b.x + (float)a.y * (float)b.y;
#endif
#else
    return c + (float)a.x * (float)b.x + (float)a.y * (float)b.y;
#endif
}

// Convert fp32 weights to fp16, transposed to [k-pair][n] layout so that the
// matvec inner loop reads 32 contiguous bytes per lane (coalesced) and uses
// v_dot2_f32_f16 (fp32 accumulate).
__global__ void prep_kernel(const float* __restrict__ dw0, const float* __restrict__ dw1,
                            const float* __restrict__ whh, const float* __restrict__ wih,
                            h2* __restrict__ ws) {
    int idx = blockIdx.x * 256 + threadIdx.x;
    if (idx >= WS_H2_TOTAL) return;
    float a, b;
    if (idx < 262144) {
        const float* src = (idx < 131072) ? dw0 : dw1;
        int r = idx & 131071;
        int k2 = r >> 9, n = r & 511;
        a = src[n * 512 + 2 * k2];
        b = src[n * 512 + 2 * k2 + 1];
    } else if (idx < 655360) {
        int r = idx - 262144;
        int k2 = r / 1536, n = r % 1536;
        a = whh[n * 512 + 2 * k2];
        b = whh[n * 512 + 2 * k2 + 1];
    } else {
        int r = idx - 655360;
        int k2 = r / 1536, n = r % 1536;
        a = wih[n * 256 + 2 * k2];
        b = wih[n * 256 + 2 * k2 + 1];
    }
    h2 v; v.x = (half_t)a; v.y = (half_t)b;
    ws[idx] = v;
}

// One matvec "pass": out[n] = sum_k in[k] * W[k][n] for a 512-wide n-block.
// 8 waves split K; lane owns 8 consecutive n; fp32 accumulation; partials
// reduced through LDS. Returns this thread's scalar s for n == tid.
__device__ __forceinline__ float mvpass(const h2* __restrict__ base, int rowstride, int K2,
                                        const h2* in2, float* red, int tid) {
    __syncthreads();  // protect red/in2 reuse from the previous pass
    const int wid = tid >> 6;
    const int lane = tid & 63;
    const int n0 = lane * 8;
    const int chunk = K2 >> 3;  // k-pairs per wave
    float a0 = 0.f, a1 = 0.f, a2 = 0.f, a3 = 0.f, a4 = 0.f, a5 = 0.f, a6 = 0.f, a7 = 0.f;
    const h2* p = base + (size_t)(wid * chunk) * rowstride + n0;
    const h2* ivp = in2 + wid * chunk;
#pragma unroll 4
    for (int i = 0; i < chunk; ++i) {
        union { f4 f; h2 v[4]; } A, B;
        A.f = *reinterpret_cast<const f4*>(p);
        B.f = *reinterpret_cast<const f4*>(p + 4);
        h2 iv = ivp[i];  // LDS broadcast (same addr across wave)
        a0 = dot2f(A.v[0], iv, a0);
        a1 = dot2f(A.v[1], iv, a1);
        a2 = dot2f(A.v[2], iv, a2);
        a3 = dot2f(A.v[3], iv, a3);
        a4 = dot2f(B.v[0], iv, a4);
        a5 = dot2f(B.v[1], iv, a5);
        a6 = dot2f(B.v[2], iv, a6);
        a7 = dot2f(B.v[3], iv, a7);
        p += rowstride;
    }
    float* rw = red + wid * 512 + n0;
    rw[0] = a0; rw[1] = a1; rw[2] = a2; rw[3] = a3;
    rw[4] = a4; rw[5] = a5; rw[6] = a6; rw[7] = a7;
    __syncthreads();
    float s = 0.f;
#pragma unroll
    for (int w = 0; w < 8; ++w) s += red[w * 512 + tid];
    return s;
}

#define PACKF(SRC)                                                             \
    do {                                                                       \
        __syncthreads();                                                       \
        if (tid < 256) {                                                       \
            h2 v_; v_.x = (half_t)SRC[2 * tid]; v_.y = (half_t)SRC[2 * tid + 1]; \
            in2[tid] = v_;                                                     \
        }                                                                      \
    } while (0)

__launch_bounds__(512, 1)
__global__ void odegru_kernel(const float* __restrict__ x, const float* __restrict__ tds,
                              const float* __restrict__ b_ih, const float* __restrict__ b_hh,
                              const float* __restrict__ db0, const float* __restrict__ db1,
                              const float* __restrict__ h0, const int* __restrict__ seq_lens,
                              const h2* __restrict__ ws, float* __restrict__ out) {
    __shared__ float hS[512], yS[512], uS[512], k1S[512], k2S[512], k3S[512];
    __shared__ h2 in2[256];
    __shared__ float red[8 * 512];
    __shared__ float giS[1536], ghS[1536];
    __shared__ float xS[256];

    const int tid = threadIdx.x;
    const int b = blockIdx.x;
    const h2* W0 = ws + W0_OFF;
    const h2* W1 = ws + W1_OFF;
    const h2* Whh = ws + WHH_OFF;
    const h2* Wih = ws + WIH_OFF;

    const int sl = seq_lens[b];
    hS[tid] = h0[tid];

    for (int t = 0; t < LL; ++t) {
        const bool valid = t < sl;
        const float td = valid ? tds[b * LL + t] : 0.f;
        if (tid < II) xS[tid] = valid ? x[((size_t)b * LL + t) * II + tid] : 0.f;
        __syncthreads();
        if (tid < II / 2) {
            h2 v; v.x = (half_t)xS[2 * tid]; v.y = (half_t)xS[2 * tid + 1];
            in2[tid] = v;
        }
        // gi = x_t @ w_ih^T + b_ih   (independent of the ODE, done first)
        for (int p = 0; p < 3; ++p) {
            float s = mvpass(Wih + p * 512, 1536, 128, in2, red, tid);
            giS[p * 512 + tid] = s + b_ih[p * 512 + tid];
        }

        // ---- ODE: one RK4(3/8) step of f(y)=tanh(tanh(y W0^T+b0) W1^T+b1)*td ----
        PACKF(hS);
        { float s = mvpass(W0, 512, 256, in2, red, tid); uS[tid] = tanhf(s + db0[tid]); }
        PACKF(uS);
        { float s = mvpass(W1, 512, 256, in2, red, tid); k1S[tid] = tanhf(s + db1[tid]) * td; }
        yS[tid] = hS[tid] + k1S[tid] * (1.f / 3.f);
        PACKF(yS);
        { float s = mvpass(W0, 512, 256, in2, red, tid); uS[tid] = tanhf(s + db0[tid]); }
        PACKF(uS);
        { float s = mvpass(W1, 512, 256, in2, red, tid); k2S[tid] = tanhf(s + db1[tid]) * td; }
        yS[tid] = hS[tid] + k2S[tid] - k1S[tid] * (1.f / 3.f);
        PACKF(yS);
        { float s = mvpass(W0, 512, 256, in2, red, tid); uS[tid] = tanhf(s + db0[tid]); }
        PACKF(uS);
        { float s = mvpass(W1, 512, 256, in2, red, tid); k3S[tid] = tanhf(s + db1[tid]) * td; }
        yS[tid] = hS[tid] + k1S[tid] - k2S[tid] + k3S[tid];
        PACKF(yS);
        { float s = mvpass(W0, 512, 256, in2, red, tid); uS[tid] = tanhf(s + db0[tid]); }
        PACKF(uS);
        {
            float s = mvpass(W1, 512, 256, in2, red, tid);
            float k4 = tanhf(s + db1[tid]) * td;
            hS[tid] = hS[tid] + (k1S[tid] + 3.f * (k2S[tid] + k3S[tid]) + k4) * 0.125f;
        }

        // ---- GRU cell on h_ode ----
        PACKF(hS);
        for (int p = 0; p < 3; ++p) {
            float s = mvpass(Whh + p * 512, 1536, 256, in2, red, tid);
            ghS[p * 512 + tid] = s + b_hh[p * 512 + tid];
        }
        // all remaining reads are same-thread-index; no sync needed here
        float r = 1.f / (1.f + __expf(-(giS[tid] + ghS[tid])));
        float z = 1.f / (1.f + __expf(-(giS[512 + tid] + ghS[512 + tid])));
        float nn = tanhf(giS[1024 + tid] + r * ghS[1024 + tid]);
        float hn = (1.f - z) * nn + z * hS[tid];
        hS[tid] = hn;
        out[((size_t)b * LL + t) * HH + tid] = hn;
        __syncthreads();
    }
}

__global__ void finalize_kernel(const int* __restrict__ seq_lens, float* __restrict__ out) {
    int b = blockIdx.x;
    int n = threadIdx.x;
    int sl = seq_lens[b];
    out[(size_t)BB * LL * HH + (size_t)b * HH + n] =
        out[((size_t)b * LL + (sl - 1)) * HH + n];
}

extern "C" void kernel_launch(void* const* d_in, const int* in_sizes, int n_in,
                              void* d_out, int out_size, void* d_ws, size_t ws_size,
                              hipStream_t stream) {
    const float* x    = (const float*)d_in[0];
    const float* tds  = (const float*)d_in[1];
    const float* w_ih = (const float*)d_in[2];
    const float* w_hh = (const float*)d_in[3];
    const float* b_ih = (const float*)d_in[4];
    const float* b_hh = (const float*)d_in[5];
    const float* dw0  = (const float*)d_in[6];
    const float* db0  = (const float*)d_in[7];
    const float* dw1  = (const float*)d_in[8];
    const float* db1  = (const float*)d_in[9];
    const float* h0   = (const float*)d_in[10];
    const int* seq_lens = (const int*)d_in[11];
    float* out = (float*)d_out;
    h2* ws = (h2*)d_ws;

    prep_kernel<<<(WS_H2_TOTAL + 255) / 256, 256, 0, stream>>>(dw0, dw1, w_hh, w_ih, ws);
    odegru_kernel<<<BB, 512, 0, stream>>>(x, tds, b_ih, b_hh, db0, db1, h0, seq_lens, ws, out);
    finalize_kernel<<<BB, 512, 0, stream>>>(seq_lens, out);
}